// Round 9
// baseline (404.082 us; speedup 1.0000x reference)
//
#include <hip/hip_runtime.h>

#define NBOND 96
#define HBS   158
#define NSTEP 288
#define NT    640
#define NW    10
#define WCOLS 316

typedef float f4 __attribute__((ext_vector_type(4)));

__device__ __forceinline__ f4 ld4(const float* p) {
  // 8B-aligned source (cols are even); two float2 loads avoid 16B-align UB
  float2 lo = *(const float2*)(p);
  float2 hi = *(const float2*)(p + 2);
  return (f4){lo.x, lo.y, hi.x, hi.y};
}

// Decomposition: wave w in [0,10) owns padded-k slice [w*32, w*32+32).
// Lane og in [0,64) owns output columns {og, og+64, og+128(if og<32)}.
// Weight chunk (a,q): row og+64a, k-sub w*32+q*4. Chunks a=0 q0-7 and
// (FBG) a=1 q0-5 live in LDS planes [plane][thread] (16B/lane contiguous,
// conflict-free); the rest stream from L2 each step (addresses loop-invariant).
// Cross-wave reduce via part[10][160]; reducer lane t<160 owns output t and
// performs all sinks (fb row write, next-x build, col-sum).
template<bool FBG>
__global__ __launch_bounds__(NT, 1)
void gcn_mp_kernel(const int* __restrict__ a2b,
                   const int* __restrict__ b2a,
                   const int* __restrict__ b2revb,
                   const float* __restrict__ f_bonds,
                   const float* __restrict__ bond_sum,
                   const float* __restrict__ W0,
                   const float* __restrict__ b0,
                   const float* __restrict__ W1, const float* __restrict__ b1,
                   const float* __restrict__ W2, const float* __restrict__ b2v,
                   const float* __restrict__ W3, const float* __restrict__ b3,
                   const float* __restrict__ W4, const float* __restrict__ b4,
                   float* __restrict__ out,
                   float* __restrict__ fbws)
{
  constexpr int LW4 = FBG ? 14 : 8;   // LDS weight planes
  constexpr int NA  = FBG ? 2  : 8;   // a=1 chunks streamed from L2

  const int m  = blockIdx.x;
  const int t  = threadIdx.x;
  const int w  = t >> 6;              // wave id 0..9 (k-slice)
  const int og = t & 63;              // lane output group

  __shared__ __align__(16) f4 Wld[LW4 * NT];
  __shared__ __align__(16) float xv[2][320];
  __shared__ float part[NW * 160];
  __shared__ int   sDp[NSTEP], sRp[NSTEP];
  __shared__ float mpb[160];
  __shared__ float hb1[112], hb2[72], hb3[40];
  __shared__ float fbl[FBG ? 1 : NBOND * HBS];

  float* const fbg = fbws + (size_t)m * (NBOND * HBS);
  auto FBld = [&](int idx) -> float {
    if constexpr (FBG) return fbg[idx]; else return fbl[idx];
  };
  auto FBst = [&](int idx, float v) {
    if constexpr (FBG) fbg[idx] = v; else fbl[idx] = v;
  };

  // ---- stage fb (row-major, unpadded [96][158])
  for (int idx = t; idx < NBOND * HBS; idx += NT)
    FBst(idx, f_bonds[m * (NBOND * HBS) + idx]);

  // ---- per-step indices + alias flag (alias with row written by prev step)
  if (t < NSTEP) {
    int i = t, c = i / 3, j = i - 3 * c;
    int a  = b2a[m * NBOND + c];
    int d  = a2b[(m * NBOND + a) * 3 + j] - 1;   // 0..95
    int rv = b2revb[m * NBOND + c];              // 0..95
    int cp = (i == 0) ? -1 : (i - 1) / 3;
    sDp[i] = d  | ((d  == cp) ? 0x10000 : 0);
    sRp[i] = rv | ((rv == cp) ? 0x10000 : 0);
  }

  // ---- weight addressing. padded-k kb -> W0 col: kb<160 -> kb ; else kb-2.
  // Wave k-slices never straddle 160 (160 = 5*32). x pads (158,159 and
  // 316..319 of padded K) are kept EXACTLY 0, so the spurious columns read
  // at the seam multiply zero — no masking needed.
  const int kb    = w * 32;
  const int cbase = kb - (kb >= 160 ? 2 : 0);

#pragma unroll
  for (int sid = 0; sid < LW4; ++sid) {
    const int a = sid >> 3, q = sid & 7;
    const int o = og + 64 * a;                  // <= 127, always valid
    Wld[sid * NT + t] = ld4(W0 + o * WCOLS + cbase + q * 4);
  }
  const float* LpA[NA];
#pragma unroll
  for (int u = 0; u < NA; ++u) {
    const int q = 8 - NA + u;
    LpA[u] = W0 + (og + 64) * WCOLS + cbase + q * 4;
  }
  const bool hasB = (og < 32);
  int oB = og + 128; if (oB > 157) oB = 157;    // rows 158/159 -> garbage, discarded
  const float* LpB[8];
#pragma unroll
  for (int q = 0; q < 8; ++q)
    LpB[q] = W0 + oB * WCOLS + cbase + q * 4;

  const float b0v = (t < HBS) ? b0[t] : 0.f;

  __syncthreads();

  // ---- build x for step 0
  if (t < 160) {
    float x0 = 0.f, bs0 = 0.f;
    if (t < HBS) {
      int d0 = sDp[0] & 0xFFFF, r0 = sRp[0] & 0xFFFF;
      x0  = FBld(t);
      bs0 = bond_sum[m * HBS + t] + FBld(d0 * HBS + t) - FBld(r0 * HBS + t);
    }
    xv[0][t]       = x0;
    xv[0][160 + t] = bs0;
  }
  __syncthreads();

  float cs = 0.f;
  int p = 0;

#pragma unroll 1
  for (int i = 0; i < NSTEP; ++i) {
    const int c  = i / 3;
    const int j  = i - 3 * c;
    const int i1 = i + 1;
    const int c1 = i1 / 3;
    const int j1 = i1 - 3 * c1;
    const bool hn = (i1 < NSTEP);

    // x slice (wave-uniform broadcast reads)
    f4 xq[8];
    const f4* XP = (const f4*)(&xv[p][w * 32]);
#pragma unroll
    for (int q = 0; q < 8; ++q) xq[q] = XP[q];

    // L2-resident weight chunks (loop-invariant addresses)
    f4 wa[NA];
#pragma unroll
    for (int u = 0; u < NA; ++u) wa[u] = ld4(LpA[u]);
    f4 wb[8];
    if (hasB) {
#pragma unroll
      for (int q = 0; q < 8; ++q) wb[q] = ld4(LpB[q]);
    }

    // reducer prefetch for next-step x (values discarded if aliased)
    float dd = 0.f, rr = 0.f, bo = 0.f, prx = 0.f;
    int aD = 0, aR = 0;
    if (t < 160 && hn) {
      const int pd = sDp[i1], pr = sRp[i1];
      const int d  = pd & 0xFFFF;  aD = pd >> 16;
      const int rv = pr & 0xFFFF;  aR = pr >> 16;
      bo = xv[p][160 + t];
      if (t < HBS) {
        dd = FBld(d * HBS + t);
        rr = FBld(rv * HBS + t);
        if (j1 == 0) prx = FBld(c1 * HBS + t);   // pristine row, race-free
      }
    }

    // ---- FMAs: 3 accumulators, static indexing
    float a0 = 0.f, a1 = 0.f, a2s = 0.f;
#pragma unroll
    for (int q = 0; q < 8; ++q) {
      const f4 v = Wld[q * NT + t];
      a0 = fmaf(v[0], xq[q][0], a0); a0 = fmaf(v[1], xq[q][1], a0);
      a0 = fmaf(v[2], xq[q][2], a0); a0 = fmaf(v[3], xq[q][3], a0);
    }
    if constexpr (FBG) {
#pragma unroll
      for (int q = 0; q < 6; ++q) {
        const f4 v = Wld[(8 + q) * NT + t];
        a1 = fmaf(v[0], xq[q][0], a1); a1 = fmaf(v[1], xq[q][1], a1);
        a1 = fmaf(v[2], xq[q][2], a1); a1 = fmaf(v[3], xq[q][3], a1);
      }
#pragma unroll
      for (int u = 0; u < 2; ++u) {
        const f4 v = wa[u];
        a1 = fmaf(v[0], xq[6 + u][0], a1); a1 = fmaf(v[1], xq[6 + u][1], a1);
        a1 = fmaf(v[2], xq[6 + u][2], a1); a1 = fmaf(v[3], xq[6 + u][3], a1);
      }
    } else {
#pragma unroll
      for (int q = 0; q < 8; ++q) {
        const f4 v = wa[q];
        a1 = fmaf(v[0], xq[q][0], a1); a1 = fmaf(v[1], xq[q][1], a1);
        a1 = fmaf(v[2], xq[q][2], a1); a1 = fmaf(v[3], xq[q][3], a1);
      }
    }
    if (hasB) {
#pragma unroll
      for (int q = 0; q < 8; ++q) {
        const f4 v = wb[q];
        a2s = fmaf(v[0], xq[q][0], a2s); a2s = fmaf(v[1], xq[q][1], a2s);
        a2s = fmaf(v[2], xq[q][2], a2s); a2s = fmaf(v[3], xq[q][3], a2s);
      }
    }

    // ---- partials (conflict-free: consecutive lanes -> consecutive dwords)
    part[w * 160 + og]      = a0;
    part[w * 160 + og + 64] = a1;
    if (hasB) part[w * 160 + og + 128] = a2s;
    __syncthreads();

    // ---- reduce + all sinks (reducer lane t owns output t)
    if (t < 160) {
      float nf = b0v;
#pragma unroll
      for (int u = 0; u < NW; ++u) nf += part[u * 160 + t];
      if (t < HBS) FBst(c * HBS + t, nf);
      if (j == 2) cs += nf;
      if (hn) {
        float xnew = (j1 == 0) ? prx : nf;
        float bsn  = bo + (aD ? nf : dd) - (aR ? nf : rr);
        if (t >= HBS) { xnew = 0.f; bsn = 0.f; }   // keep x pads exactly 0
        xv[p ^ 1][t]       = xnew;
        xv[p ^ 1][160 + t] = bsn;
      }
    }
    p ^= 1;
    __syncthreads();
  }

  // ---- mp = final column sums (accumulated at j==2 steps)
  if (t < 160) mpb[t] = (t < HBS) ? cs : 0.f;
  __syncthreads();

  // ---- tiny MLP: 158 -> 110 (no relu) -> 70 (relu) -> 35 (relu) -> 1
  if (t < 110) {
    float acc = b1[t];
    for (int k = 0; k < HBS; ++k) acc = fmaf(mpb[k], W1[t * HBS + k], acc);
    hb1[t] = acc;
  }
  __syncthreads();
  if (t < 70) {
    float acc = b2v[t];
    for (int k = 0; k < 110; ++k) acc = fmaf(hb1[k], W2[t * 110 + k], acc);
    hb2[t] = fmaxf(acc, 0.f);
  }
  __syncthreads();
  if (t < 35) {
    float acc = b3[t];
    for (int k = 0; k < 70; ++k) acc = fmaf(hb2[k], W3[t * 70 + k], acc);
    hb3[t] = fmaxf(acc, 0.f);
  }
  __syncthreads();
  if (t == 0) {
    float acc = b4[0];
    for (int k = 0; k < 35; ++k) acc = fmaf(hb3[k], W4[k], acc);
    out[m] = acc;
  }
}

extern "C" void kernel_launch(void* const* d_in, const int* in_sizes, int n_in,
                              void* d_out, int out_size, void* d_ws, size_t ws_size,
                              hipStream_t stream)
{
  const int*   a2b      = (const int*)d_in[0];
  const int*   b2a      = (const int*)d_in[1];
  const int*   b2revb   = (const int*)d_in[2];
  const float* f_bonds  = (const float*)d_in[3];
  /* d_in[4] = f_atoms_ (unused by forward) */
  const float* bond_sum = (const float*)d_in[5];
  const float* W0 = (const float*)d_in[6];
  const float* b0 = (const float*)d_in[7];
  const float* W1 = (const float*)d_in[8];
  const float* b1 = (const float*)d_in[9];
  const float* W2 = (const float*)d_in[10];
  const float* b2 = (const float*)d_in[11];
  const float* W3 = (const float*)d_in[12];
  const float* b3 = (const float*)d_in[13];
  const float* W4 = (const float*)d_in[14];
  const float* b4 = (const float*)d_in[15];

  const size_t need = (size_t)96 * NBOND * HBS * sizeof(float);  // 5.83 MB
  if (ws_size >= need) {
    gcn_mp_kernel<true><<<dim3(96), dim3(NT), 0, stream>>>(
        a2b, b2a, b2revb, f_bonds, bond_sum,
        W0, b0, W1, b1, W2, b2, W3, b3, W4, b4,
        (float*)d_out, (float*)d_ws);
  } else {
    gcn_mp_kernel<false><<<dim3(96), dim3(NT), 0, stream>>>(
        a2b, b2a, b2revb, f_bonds, bond_sum,
        W0, b0, W1, b1, W2, b2, W3, b3, W4, b4,
        (float*)d_out, (float*)d_ws);
  }
}